// Round 1
// baseline (6864.361 us; speedup 1.0000x reference)
//
#include <hip/hip_runtime.h>
#include <cmath>

// ---------------------------------------------------------------------------
// 2-layer LSTM, T=256 B=64 D=H=1024, fully fused into ONE persistent kernel.
//
// Layouts (identical fragment conventions to the previously-verified kernel):
//  packed gate col p = h*4 + g   (g: 0=i,1=j,2=f,3=o ; orig col = g*1024+h)
//  A-pack (64 x K):  AP[mt][kt][lane][j] = A[mt*16 + (lane&15)][kt*32 + (lane>>4)*8 + j]
//  B-pack (K x G):   WP[nt][kt][lane][j] = W[kt*32 + (lane>>4)*8 + j][origcol(nt*16 + (lane&15))]
//  MFMA 16x16x32 f16: D[row=(lane>>4)*4+r][col=lane&15]
//
// Persistent kernel: 256 blocks x 1024 threads (16 waves), 1 block/CU.
//  - blocks [0,128):  layer 0, colgroup cg = 32 packed gate cols, K = 2048 ([x_t | h1_{t-1}])
//  - blocks [128,256): layer 1, same cols,                K = 2048 ([h1_{t-1} | h2_{t-2}])
//  - weights for the block's 2 n-tiles (2048x32 fp16 = 128 KB) live in LDS for all 256 steps
//  - 16 waves = 4 m-tiles x 4 K-quarters; each wave reads a disjoint K-quarter of A
//    (A-operand read exactly once per CU per step), 2 n-tiles per wave reuse the a-frag.
//  - partial C tiles combined via LDS fp32 atomics; gate math on 512 threads; c in registers.
//  - layers pipelined: super-step s runs layer0 step s and layer1 step s-1 -> 257 grid barriers.
//  - no xgemm, no Z buffer: the x-parts are folded into the K=2048 recurrent GEMM.
// ---------------------------------------------------------------------------

typedef _Float16 half8 __attribute__((ext_vector_type(8)));
typedef float f32x4 __attribute__((ext_vector_type(4)));

constexpr int Tt = 256, Gg = 4096;
constexpr size_t HPACK = 65536;            // halves in one 64x1024 A-pack slab
constexpr int NBLK = 256;
constexpr unsigned WLDS_BYTES = 131072;    // 2 nt x 64 kt x 64 lane x 8 halves x 2B
constexpr unsigned ZP_FLOATS = 8 * 16 * 17;          // [mt*2+nl][16][17] padded
constexpr unsigned SMEM_BYTES = WLDS_BYTES + ZP_FLOATS * 4;   // 139776 B

__device__ __forceinline__ float sigmoidf_(float x) { return 1.f / (1.f + expf(-x)); }

// ---- pack W (fp32 [2048][4096]) -> full-K fp16 B-pack ----------------------
__global__ void pack_w_kernel(const float* __restrict__ W0, const float* __restrict__ W1,
                              _Float16* __restrict__ WP0, _Float16* __restrict__ WP1) {
    int idx = blockIdx.x * 256 + threadIdx.x;      // [0, 2^20)
    const float* src = blockIdx.y ? W1 : W0;
    _Float16* dst = blockIdx.y ? WP1 : WP0;
    int lane = idx & 63;
    int kt = (idx >> 6) & 63;
    int nt = idx >> 12;
    int p = nt * 16 + (lane & 15);
    int col = (p & 3) * 1024 + (p >> 2);
    int kbase = kt * 32 + (lane >> 4) * 8;
    half8 v;
#pragma unroll
    for (int j = 0; j < 8; ++j) v[j] = (_Float16)src[(size_t)(kbase + j) * Gg + col];
    *reinterpret_cast<half8*>(dst + (size_t)idx * 8) = v;
}

__global__ void pack_bias_kernel(const float* __restrict__ b0, const float* __restrict__ b1,
                                 float* __restrict__ bp0, float* __restrict__ bp1) {
    int idx = blockIdx.x * 256 + threadIdx.x;      // [0, 8192)
    int l = idx >> 12, p = idx & 4095;
    int col = (p & 3) * 1024 + (p >> 2);
    (l ? bp1 : bp0)[p] = (l ? b1 : b0)[col];
}

// ---- pack X: fp32 [16384][1024] -> fp16 A-pack -----------------------------
__global__ void pack_a_kernel(const float* __restrict__ X, _Float16* __restrict__ XP) {
    int idx = blockIdx.x * 256 + threadIdx.x;      // [0, 1024*32*64)
    int lane = idx & 63;
    int kt = (idx >> 6) & 31;
    int mt = idx >> 11;
    int m = mt * 16 + (lane & 15);
    int kbase = kt * 32 + (lane >> 4) * 8;
    const float* srow = X + (size_t)m * 1024 + kbase;
    half8 v;
#pragma unroll
    for (int j = 0; j < 8; ++j) v[j] = (_Float16)srow[j];
    *reinterpret_cast<half8*>(XP + (size_t)idx * 8) = v;
}

// ---- grid barrier (agent scope, generation counter, spin-timeout bail) -----
__device__ __forceinline__ void grid_barrier(unsigned* cnt, unsigned* gen) {
    __syncthreads();
    if (threadIdx.x == 0) {
        unsigned g = __hip_atomic_load(gen, __ATOMIC_RELAXED, __HIP_MEMORY_SCOPE_AGENT);
        unsigned arr = __hip_atomic_fetch_add(cnt, 1u, __ATOMIC_ACQ_REL, __HIP_MEMORY_SCOPE_AGENT);
        if (arr == NBLK - 1) {
            __hip_atomic_store(cnt, 0u, __ATOMIC_RELAXED, __HIP_MEMORY_SCOPE_AGENT);
            __hip_atomic_store(gen, g + 1u, __ATOMIC_RELEASE, __HIP_MEMORY_SCOPE_AGENT);
        } else {
            unsigned spins = 0;
            while (__hip_atomic_load(gen, __ATOMIC_RELAXED, __HIP_MEMORY_SCOPE_AGENT) == g) {
                __builtin_amdgcn_s_sleep(2);
                if (++spins > (1u << 24)) break;   // safety bail: never hang the harness
            }
            __builtin_amdgcn_fence(__ATOMIC_ACQUIRE, "agent");
        }
    }
    __syncthreads();
}

struct FArgs {
    const _Float16* XP;
    const _Float16* WP0;
    const _Float16* WP1;
    const float* bp0;
    const float* bp1;
    _Float16* h1p;     // 2 parity slabs of HPACK halves
    _Float16* h2p;     // 2 parity slabs
    float* out;
    unsigned* bar;     // [0]=cnt [1]=gen
};

__global__ __launch_bounds__(1024, 4) void lstm_fused(FArgs a) {
    extern __shared__ char smem[];
    _Float16* wlds = (_Float16*)smem;                          // 128 KB weights
    float* zp = (float*)(smem + WLDS_BYTES);                   // [8][16][17] f32

    const int tid = threadIdx.x;
    const int layer = blockIdx.x >> 7;     // 0 or 1
    const int cg = blockIdx.x & 127;       // colgroup: packed cols [cg*32, cg*32+32)

    // ---- stage this block's weight slice (2 n-tiles, contiguous in B-pack) ----
    const _Float16* wsrc = (layer ? a.WP1 : a.WP0) + (size_t)cg * 65536;
    for (int i = tid; i < 8192; i += 1024)
        ((half8*)wlds)[i] = ((const half8*)wsrc)[i];
    for (int i = tid; i < (int)ZP_FLOATS; i += 1024) zp[i] = 0.f;

    // ---- per-gate-thread persistent state ----
    float creg = 0.f;
    float bias4[4] = {0.f, 0.f, 0.f, 0.f};
    if (tid < 512) {
        int hl = tid & 7;
        const float* bp = layer ? a.bp1 : a.bp0;
#pragma unroll
        for (int g = 0; g < 4; ++g) bias4[g] = bp[cg * 32 + hl * 4 + g];
    }
    __syncthreads();

    const int lane = tid & 63, wv = tid >> 6;
    const int mt = wv & 3, kq = wv >> 2;           // 4 m-tiles x 4 K-quarters
    const int r0 = (lane >> 4) * 4, ccc = lane & 15;
    const int ktL = (kq & 1) * 16;                 // kt offset within the 32-kt source slab

    for (int s = 0; s <= Tt; ++s) {
        const bool act = layer ? (s >= 1) : (s < Tt);
        if (act) {
            const _Float16* h1prev = a.h1p + (size_t)((s + 1) & 1) * HPACK;
            const _Float16* srcA;
            if (layer == 0)
                srcA = (kq < 2) ? (a.XP + (size_t)s * HPACK) : h1prev;           // [x_t | h1_{t-1}]
            else
                srcA = (kq < 2) ? h1prev : (a.h2p + (size_t)(s & 1) * HPACK);    // [h1_{t-1} | h2_{t-2}]

            const half8* ap = (const half8*)srcA + ((size_t)mt * 32 + ktL) * 64 + lane;
            const half8* bq0 = (const half8*)wlds + ((size_t)(0 * 64 + kq * 16)) * 64 + lane;
            const half8* bq1 = (const half8*)wlds + ((size_t)(1 * 64 + kq * 16)) * 64 + lane;
            f32x4 ac0 = {0.f, 0.f, 0.f, 0.f}, ac1 = {0.f, 0.f, 0.f, 0.f};
#pragma unroll
            for (int i = 0; i < 16; ++i) {
                half8 av = ap[i * 64];
                ac0 = __builtin_amdgcn_mfma_f32_16x16x32_f16(av, bq0[i * 64], ac0, 0, 0, 0);
                ac1 = __builtin_amdgcn_mfma_f32_16x16x32_f16(av, bq1[i * 64], ac1, 0, 0, 0);
            }
#pragma unroll
            for (int r = 0; r < 4; ++r) {
                atomicAdd(&zp[((mt * 2 + 0) * 16 + r0 + r) * 17 + ccc], ac0[r]);
                atomicAdd(&zp[((mt * 2 + 1) * 16 + r0 + r) * 17 + ccc], ac1[r]);
            }
        }
        __syncthreads();
        if (act && tid < 512) {
            int b = tid >> 3, hl = tid & 7;
            float z[4];
#pragma unroll
            for (int g = 0; g < 4; ++g) {
                int c = hl * 4 + g;
                z[g] = zp[(((b >> 4) * 2 + (c >> 4)) * 16 + (b & 15)) * 17 + (c & 15)] + bias4[g];
            }
            float cn = creg * sigmoidf_(z[2] + 1.0f) + sigmoidf_(z[0]) * tanhf(z[1]);
            float hn = tanhf(cn) * sigmoidf_(z[3]);
            creg = cn;
            int k = cg * 8 + hl;                                   // h column index
            _Float16* hdst = layer ? (a.h2p + (size_t)((s + 1) & 1) * HPACK)
                                   : (a.h1p + (size_t)(s & 1) * HPACK);
            hdst[(((size_t)(b >> 4) * 32 + (k >> 5)) * 64 + ((k >> 3) & 3) * 16 + (b & 15)) * 8 + (k & 7)] =
                (_Float16)hn;
            if (layer) a.out[(size_t)(s - 1) * 65536 + (size_t)b * 1024 + k] = hn;
        }
        __syncthreads();
        for (int i = tid; i < (int)ZP_FLOATS; i += 1024) zp[i] = 0.f;   // re-zero for next step
        grid_barrier(a.bar, a.bar + 1);
    }
}

// ---------------------------------------------------------------------------
extern "C" void kernel_launch(void* const* d_in, const int* in_sizes, int n_in,
                              void* d_out, int out_size, void* d_ws, size_t ws_size,
                              hipStream_t stream) {
    const float* X  = (const float*)d_in[0];
    const float* W0 = (const float*)d_in[1];
    const float* b0 = (const float*)d_in[2];
    const float* W1 = (const float*)d_in[3];
    const float* b1 = (const float*)d_in[4];
    float* out = (float*)d_out;

    char* ws = (char*)d_ws;
    size_t off = 0;
    auto take = [&](size_t n) -> void* {
        void* r = ws + off;
        off += (n + 255) & ~(size_t)255;
        return r;
    };

    const size_t WPB = (size_t)2048 * Gg * 2;            // 16 MiB per packed W
    _Float16* WP0 = (_Float16*)take(WPB);
    _Float16* WP1 = (_Float16*)take(WPB);
    float* bp0 = (float*)take(Gg * 4);
    float* bp1 = (float*)take(Gg * 4);
    const size_t APB = (size_t)Tt * 64 * 1024 * 2;       // 32 MiB X A-pack
    _Float16* XP = (_Float16*)take(APB);
    _Float16* h1p = (_Float16*)take(2 * HPACK * 2);      // 256 KiB (2 parity slabs)
    _Float16* h2p = (_Float16*)take(2 * HPACK * 2);
    unsigned* bar = (unsigned*)take(256);

    hipMemsetAsync(h1p, 0, 2 * HPACK * 2, stream);
    hipMemsetAsync(h2p, 0, 2 * HPACK * 2, stream);
    hipMemsetAsync(bar, 0, 256, stream);

    pack_w_kernel<<<dim3(4096, 2), 256, 0, stream>>>(W0, W1, WP0, WP1);
    pack_bias_kernel<<<32, 256, 0, stream>>>(b0, b1, bp0, bp1);
    pack_a_kernel<<<8192, 256, 0, stream>>>(X, XP);

    hipFuncSetAttribute((const void*)lstm_fused,
                        hipFuncAttributeMaxDynamicSharedMemorySize, SMEM_BYTES);

    FArgs fa{XP, WP0, WP1, bp0, bp1, h1p, h2p, out, bar};
    void* kp[] = {&fa};
    hipError_t e = hipLaunchCooperativeKernel((const void*)lstm_fused, dim3(NBLK), dim3(1024),
                                              kp, SMEM_BYTES, stream);
    if (e != hipSuccess) {
        // fallback: plain launch — 256 blocks x 1 block/CU fit co-resident on 256 CUs;
        // the barrier has a spin-timeout so a residency failure cannot hang.
        lstm_fused<<<dim3(NBLK), dim3(1024), SMEM_BYTES, stream>>>(fa);
    }
    (void)in_sizes; (void)n_in; (void)out_size; (void)ws_size;
}

// Round 2
// 4464.961 us; speedup vs baseline: 1.5374x; 1.5374x over previous
//
#include <hip/hip_runtime.h>
#include <cmath>

// ---------------------------------------------------------------------------
// 2-layer LSTM, T=256 B=64 D=H=1024, ONE persistent kernel, fence-free hot loop.
//
// Round-2 change vs round-1: the per-step cost was agent-fence cache maintenance
// (per-block buffer_wbl2 + buffer_inv, ~26.5 us/step). Now:
//   - h1/h2 cross-block state moves through the LLC explicitly:
//       stores: packed 4B __hip_atomic_store(RELAXED, AGENT)  (write-through)
//       loads:  asm global_load_dwordx4 ... sc0 sc1           (LLC-coherent read)
//   - grid barrier: all RELAXED atomics (memory-side RMW at LLC), no fences,
//     cnt/gen on separate cache lines, sc1 spin loads.
//   - all plain-cached data (XP, WP->LDS, out) is immutable or write-only
//     during the kernel -> no wbl2/inv anywhere in the loop.
//
// Layouts (unchanged, verified):
//  packed gate col p = h*4 + g   (g: 0=i,1=j,2=f,3=o ; orig col = g*1024+h)
//  A-pack (64 x K):  AP[mt][kt][lane][j] = A[mt*16 + (lane&15)][kt*32 + (lane>>4)*8 + j]
//  B-pack (K x G):   WP[nt][kt][lane][j] = W[kt*32 + (lane>>4)*8 + j][origcol(nt*16 + (lane&15))]
//  MFMA 16x16x32 f16: D[row=(lane>>4)*4+r][col=lane&15]
// ---------------------------------------------------------------------------

typedef _Float16 half8 __attribute__((ext_vector_type(8)));
typedef float f32x4 __attribute__((ext_vector_type(4)));
typedef unsigned int uint4v __attribute__((ext_vector_type(4)));

constexpr int Tt = 256, Gg = 4096;
constexpr size_t HPACK = 65536;            // halves in one 64x1024 A-pack slab
constexpr int NBLK = 256;
constexpr unsigned WLDS_BYTES = 131072;    // 2 nt x 64 kt x 64 lane x 8 halves x 2B
constexpr unsigned ZP_FLOATS = 8 * 16 * 17;          // [mt*2+nl][16][17] padded
constexpr unsigned HSTAGE_BYTES = 64 * 8 * 2;        // 1 KiB h staging
constexpr unsigned SMEM_BYTES = WLDS_BYTES + ZP_FLOATS * 4 + HSTAGE_BYTES;

__device__ __forceinline__ float sigmoidf_(float x) { return 1.f / (1.f + expf(-x)); }

// ---- pack W (fp32 [2048][4096]) -> full-K fp16 B-pack ----------------------
__global__ void pack_w_kernel(const float* __restrict__ W0, const float* __restrict__ W1,
                              _Float16* __restrict__ WP0, _Float16* __restrict__ WP1) {
    int idx = blockIdx.x * 256 + threadIdx.x;      // [0, 2^20)
    const float* src = blockIdx.y ? W1 : W0;
    _Float16* dst = blockIdx.y ? WP1 : WP0;
    int lane = idx & 63;
    int kt = (idx >> 6) & 63;
    int nt = idx >> 12;
    int p = nt * 16 + (lane & 15);
    int col = (p & 3) * 1024 + (p >> 2);
    int kbase = kt * 32 + (lane >> 4) * 8;
    half8 v;
#pragma unroll
    for (int j = 0; j < 8; ++j) v[j] = (_Float16)src[(size_t)(kbase + j) * Gg + col];
    *reinterpret_cast<half8*>(dst + (size_t)idx * 8) = v;
}

__global__ void pack_bias_kernel(const float* __restrict__ b0, const float* __restrict__ b1,
                                 float* __restrict__ bp0, float* __restrict__ bp1) {
    int idx = blockIdx.x * 256 + threadIdx.x;      // [0, 8192)
    int l = idx >> 12, p = idx & 4095;
    int col = (p & 3) * 1024 + (p >> 2);
    (l ? bp1 : bp0)[p] = (l ? b1 : b0)[col];
}

// ---- pack X: fp32 [16384][1024] -> fp16 A-pack -----------------------------
__global__ void pack_a_kernel(const float* __restrict__ X, _Float16* __restrict__ XP) {
    int idx = blockIdx.x * 256 + threadIdx.x;      // [0, 1024*32*64)
    int lane = idx & 63;
    int kt = (idx >> 6) & 31;
    int mt = idx >> 11;
    int m = mt * 16 + (lane & 15);
    int kbase = kt * 32 + (lane >> 4) * 8;
    const float* srow = X + (size_t)m * 1024 + kbase;
    half8 v;
#pragma unroll
    for (int j = 0; j < 8; ++j) v[j] = (_Float16)srow[j];
    *reinterpret_cast<half8*>(XP + (size_t)idx * 8) = v;
}

// ---- relaxed grid barrier: memory-side RMWs at LLC, NO fences --------------
// cnt at word 0, gen at word 64 (separate 256B lines).
__device__ __forceinline__ void grid_barrier_relaxed(unsigned* bar) {
    __syncthreads();   // compiler drains vmcnt before s_barrier -> h stores complete
    if (threadIdx.x == 0) {
        unsigned* cnt = bar;
        unsigned* gen = bar + 64;
        unsigned g = __hip_atomic_load(gen, __ATOMIC_RELAXED, __HIP_MEMORY_SCOPE_AGENT);
        unsigned arr = __hip_atomic_fetch_add(cnt, 1u, __ATOMIC_RELAXED, __HIP_MEMORY_SCOPE_AGENT);
        if (arr == NBLK - 1) {
            __hip_atomic_store(cnt, 0u, __ATOMIC_RELAXED, __HIP_MEMORY_SCOPE_AGENT);
            __hip_atomic_store(gen, g + 1u, __ATOMIC_RELAXED, __HIP_MEMORY_SCOPE_AGENT);
        } else {
            unsigned spins = 0;
            while (__hip_atomic_load(gen, __ATOMIC_RELAXED, __HIP_MEMORY_SCOPE_AGENT) == g) {
                __builtin_amdgcn_s_sleep(2);
                if (++spins > (1u << 20)) break;   // safety bail: never hang the harness
            }
        }
    }
    __syncthreads();
}

struct FArgs {
    const _Float16* XP;
    const _Float16* WP0;
    const _Float16* WP1;
    const float* bp0;
    const float* bp1;
    _Float16* h1p;     // 2 parity slabs of HPACK halves
    _Float16* h2p;     // 2 parity slabs
    float* out;
    unsigned* bar;
};

__global__ __launch_bounds__(1024, 4) void lstm_fused(FArgs a) {
    extern __shared__ char smem[];
    _Float16* wlds = (_Float16*)smem;                          // 128 KB weights
    float* zp = (float*)(smem + WLDS_BYTES);                   // [8][16][17] f32
    _Float16* hstage = (_Float16*)(smem + WLDS_BYTES + ZP_FLOATS * 4);   // [64][8]

    const int tid = threadIdx.x;
    const int layer = blockIdx.x >> 7;     // 0 or 1
    const int cg = blockIdx.x & 127;       // colgroup: packed cols [cg*32, cg*32+32)

    // ---- stage this block's weight slice (2 n-tiles, contiguous in B-pack) ----
    const _Float16* wsrc = (layer ? a.WP1 : a.WP0) + (size_t)cg * 65536;
    for (int i = tid; i < 8192; i += 1024)
        ((half8*)wlds)[i] = ((const half8*)wsrc)[i];
    for (int i = tid; i < (int)ZP_FLOATS; i += 1024) zp[i] = 0.f;

    // ---- per-gate-thread persistent state ----
    float creg = 0.f;
    float bias4[4] = {0.f, 0.f, 0.f, 0.f};
    if (tid < 512) {
        int hl = tid & 7;
        const float* bp = layer ? a.bp1 : a.bp0;
#pragma unroll
        for (int g = 0; g < 4; ++g) bias4[g] = bp[cg * 32 + hl * 4 + g];
    }
    __syncthreads();

    const int lane = tid & 63, wv = tid >> 6;
    const int mt = wv & 3, kq = wv >> 2;           // 4 m-tiles x 4 K-quarters
    const int r0 = (lane >> 4) * 4, ccc = lane & 15;
    const int ktL = (kq & 1) * 16;                 // kt offset within the 32-kt source slab

    for (int s = 0; s <= Tt; ++s) {
        const bool act = layer ? (s >= 1) : (s < Tt);
        if (act) {
            const _Float16* h1prev = a.h1p + (size_t)((s + 1) & 1) * HPACK;
            const _Float16* srcA;
            bool llc;
            if (layer == 0) {
                llc = (kq >= 2);
                srcA = (kq < 2) ? (a.XP + (size_t)s * HPACK) : h1prev;           // [x_t | h1_{t-1}]
            } else {
                llc = true;
                srcA = (kq < 2) ? h1prev : (a.h2p + (size_t)(s & 1) * HPACK);    // [h1_{t-1} | h2_{t-2}]
            }
            const _Float16* apF = srcA + (((size_t)mt * 32 + ktL) * 64 + lane) * 8;
            const half8* bq0 = (const half8*)wlds + ((size_t)(0 * 64 + kq * 16)) * 64 + lane;
            const half8* bq1 = (const half8*)wlds + ((size_t)(1 * 64 + kq * 16)) * 64 + lane;

            uint4v av[16];
            if (llc) {
#pragma unroll
                for (int i = 0; i < 16; ++i)
                    asm volatile("global_load_dwordx4 %0, %1, off sc0 sc1"
                                 : "=v"(av[i]) : "v"(apF + (size_t)i * 512));
                asm volatile("s_waitcnt vmcnt(0)" ::: "memory");
                __builtin_amdgcn_sched_barrier(0);
            } else {
#pragma unroll
                for (int i = 0; i < 16; ++i)
                    av[i] = *reinterpret_cast<const uint4v*>(apF + (size_t)i * 512);
            }

            f32x4 ac0 = {0.f, 0.f, 0.f, 0.f}, ac1 = {0.f, 0.f, 0.f, 0.f};
#pragma unroll
            for (int i = 0; i < 16; ++i) {
                half8 a8 = __builtin_bit_cast(half8, av[i]);
                ac0 = __builtin_amdgcn_mfma_f32_16x16x32_f16(a8, bq0[i * 64], ac0, 0, 0, 0);
                ac1 = __builtin_amdgcn_mfma_f32_16x16x32_f16(a8, bq1[i * 64], ac1, 0, 0, 0);
            }
#pragma unroll
            for (int r = 0; r < 4; ++r) {
                atomicAdd(&zp[((mt * 2 + 0) * 16 + r0 + r) * 17 + ccc], ac0[r]);
                atomicAdd(&zp[((mt * 2 + 1) * 16 + r0 + r) * 17 + ccc], ac1[r]);
            }
        }
        __syncthreads();
        if (act && tid < 512) {
            int b = tid >> 3, hl = tid & 7;
            float z[4];
#pragma unroll
            for (int g = 0; g < 4; ++g) {
                int c = hl * 4 + g;
                z[g] = zp[(((b >> 4) * 2 + (c >> 4)) * 16 + (b & 15)) * 17 + (c & 15)] + bias4[g];
            }
            float cn = creg * sigmoidf_(z[2] + 1.0f) + sigmoidf_(z[0]) * tanhf(z[1]);
            float hn = tanhf(cn) * sigmoidf_(z[3]);
            creg = cn;
            hstage[b * 8 + hl] = (_Float16)hn;
            if (layer) a.out[(size_t)(s - 1) * 65536 + (size_t)b * 1024 + (cg * 8 + hl)] = hn;
        }
        __syncthreads();
        if (act && tid < 256) {
            // pack 2 halves -> one 4B agent-scope (write-through) store into A-pack layout
            int b = tid >> 2, pr = tid & 3;
            unsigned lo = (unsigned)__builtin_bit_cast(unsigned short, hstage[b * 8 + 2 * pr]);
            unsigned hi = (unsigned)__builtin_bit_cast(unsigned short, hstage[b * 8 + 2 * pr + 1]);
            unsigned val = lo | (hi << 16);
            _Float16* hdst = layer ? (a.h2p + (size_t)((s + 1) & 1) * HPACK)
                                   : (a.h1p + (size_t)(s & 1) * HPACK);
            size_t dw = (((size_t)(b >> 4) * 32 + (cg >> 2)) * 64 + (size_t)(cg & 3) * 16 + (b & 15)) * 4 + pr;
            __hip_atomic_store((unsigned*)hdst + dw, val, __ATOMIC_RELAXED, __HIP_MEMORY_SCOPE_AGENT);
        }
        for (int i = tid; i < (int)ZP_FLOATS; i += 1024) zp[i] = 0.f;   // re-zero for next step
        grid_barrier_relaxed(a.bar);
    }
}

// ---------------------------------------------------------------------------
extern "C" void kernel_launch(void* const* d_in, const int* in_sizes, int n_in,
                              void* d_out, int out_size, void* d_ws, size_t ws_size,
                              hipStream_t stream) {
    const float* X  = (const float*)d_in[0];
    const float* W0 = (const float*)d_in[1];
    const float* b0 = (const float*)d_in[2];
    const float* W1 = (const float*)d_in[3];
    const float* b1 = (const float*)d_in[4];
    float* out = (float*)d_out;

    char* ws = (char*)d_ws;
    size_t off = 0;
    auto take = [&](size_t n) -> void* {
        void* r = ws + off;
        off += (n + 255) & ~(size_t)255;
        return r;
    };

    const size_t WPB = (size_t)2048 * Gg * 2;            // 16 MiB per packed W
    _Float16* WP0 = (_Float16*)take(WPB);
    _Float16* WP1 = (_Float16*)take(WPB);
    float* bp0 = (float*)take(Gg * 4);
    float* bp1 = (float*)take(Gg * 4);
    const size_t APB = (size_t)Tt * 64 * 1024 * 2;       // 32 MiB X A-pack
    _Float16* XP = (_Float16*)take(APB);
    _Float16* h1p = (_Float16*)take(2 * HPACK * 2);      // 256 KiB (2 parity slabs)
    _Float16* h2p = (_Float16*)take(2 * HPACK * 2);
    unsigned* bar = (unsigned*)take(512);

    hipMemsetAsync(h1p, 0, 2 * HPACK * 2, stream);
    hipMemsetAsync(h2p, 0, 2 * HPACK * 2, stream);
    hipMemsetAsync(bar, 0, 512, stream);

    pack_w_kernel<<<dim3(4096, 2), 256, 0, stream>>>(W0, W1, WP0, WP1);
    pack_bias_kernel<<<32, 256, 0, stream>>>(b0, b1, bp0, bp1);
    pack_a_kernel<<<8192, 256, 0, stream>>>(X, XP);

    hipFuncSetAttribute((const void*)lstm_fused,
                        hipFuncAttributeMaxDynamicSharedMemorySize, SMEM_BYTES);

    FArgs fa{XP, WP0, WP1, bp0, bp1, h1p, h2p, out, bar};
    void* kp[] = {&fa};
    hipError_t e = hipLaunchCooperativeKernel((const void*)lstm_fused, dim3(NBLK), dim3(1024),
                                              kp, SMEM_BYTES, stream);
    if (e != hipSuccess) {
        lstm_fused<<<dim3(NBLK), dim3(1024), SMEM_BYTES, stream>>>(fa);
    }
    (void)in_sizes; (void)n_in; (void)out_size; (void)ws_size;
}

// Round 3
// 3979.102 us; speedup vs baseline: 1.7251x; 1.1221x over previous
//
#include <hip/hip_runtime.h>
#include <cmath>

// ---------------------------------------------------------------------------
// 2-layer LSTM, T=256 B=64 D=H=1024, ONE persistent kernel, NO global barrier.
//
// Round-3 design:
//  - h1/h2 state in never-reused ring buffers (one 128 KB slab per timestep).
//    Readers use PLAIN CACHED loads (no address reuse -> no stale L2 copies);
//    writers use relaxed agent-scope 4B atomic stores (write-through to LLC).
//  - No grid barrier. Per-step readiness via replicated counters:
//    h1ready[t], h2ready[t] x 8 replicas; each producing block +1 on every
//    replica after its h stores drain. Consumer waves wait via one scout lane
//    polling a replica (16 blocks/replica) -> LDS token -> siblings spin LDS.
//  - Layer-0 XP-waves never wait; layers fully decoupled (self-timed pipeline).
//
// Layouts (unchanged, verified):
//  packed gate col p = h*4 + g   (g: 0=i,1=j,2=f,3=o ; orig col = g*1024+h)
//  A-pack (64 x K):  AP[mt][kt][lane][j] = A[mt*16 + (lane&15)][kt*32 + (lane>>4)*8 + j]
//  B-pack (K x G):   WP[nt][kt][lane][j] = W[kt*32 + (lane>>4)*8 + j][origcol(nt*16 + (lane&15))]
//  MFMA 16x16x32 f16: D[row=(lane>>4)*4+r][col=lane&15]
// ---------------------------------------------------------------------------

typedef _Float16 half8 __attribute__((ext_vector_type(8)));
typedef float f32x4 __attribute__((ext_vector_type(4)));

constexpr int Tt = 256, Gg = 4096;
constexpr size_t HPACK = 65536;            // halves in one 64x1024 A-pack slab
constexpr int NBLK = 256;
constexpr unsigned WLDS_BYTES = 131072;    // 2 nt x 64 kt x 64 lane x 8 halves x 2B
constexpr unsigned ZP_FLOATS = 8 * 16 * 17;          // [mt*2+nl][16][17] padded
constexpr unsigned HSTAGE_BYTES = 64 * 8 * 2;        // 1 KiB h staging
constexpr unsigned SMEM_BYTES = WLDS_BYTES + ZP_FLOATS * 4 + HSTAGE_BYTES + 16;

__device__ __forceinline__ float sigmoidf_(float x) { return 1.f / (1.f + expf(-x)); }

// ---- pack W (fp32 [2048][4096]) -> full-K fp16 B-pack ----------------------
__global__ void pack_w_kernel(const float* __restrict__ W0, const float* __restrict__ W1,
                              _Float16* __restrict__ WP0, _Float16* __restrict__ WP1) {
    int idx = blockIdx.x * 256 + threadIdx.x;      // [0, 2^20)
    const float* src = blockIdx.y ? W1 : W0;
    _Float16* dst = blockIdx.y ? WP1 : WP0;
    int lane = idx & 63;
    int kt = (idx >> 6) & 63;
    int nt = idx >> 12;
    int p = nt * 16 + (lane & 15);
    int col = (p & 3) * 1024 + (p >> 2);
    int kbase = kt * 32 + (lane >> 4) * 8;
    half8 v;
#pragma unroll
    for (int j = 0; j < 8; ++j) v[j] = (_Float16)src[(size_t)(kbase + j) * Gg + col];
    *reinterpret_cast<half8*>(dst + (size_t)idx * 8) = v;
}

__global__ void pack_bias_kernel(const float* __restrict__ b0, const float* __restrict__ b1,
                                 float* __restrict__ bp0, float* __restrict__ bp1) {
    int idx = blockIdx.x * 256 + threadIdx.x;      // [0, 8192)
    int l = idx >> 12, p = idx & 4095;
    int col = (p & 3) * 1024 + (p >> 2);
    (l ? bp1 : bp0)[p] = (l ? b1 : b0)[col];
}

// ---- pack X: fp32 [16384][1024] -> fp16 A-pack -----------------------------
__global__ void pack_a_kernel(const float* __restrict__ X, _Float16* __restrict__ XP) {
    int idx = blockIdx.x * 256 + threadIdx.x;      // [0, 1024*32*64)
    int lane = idx & 63;
    int kt = (idx >> 6) & 31;
    int mt = idx >> 11;
    int m = mt * 16 + (lane & 15);
    int kbase = kt * 32 + (lane >> 4) * 8;
    const float* srow = X + (size_t)m * 1024 + kbase;
    half8 v;
#pragma unroll
    for (int j = 0; j < 8; ++j) v[j] = (_Float16)srow[j];
    *reinterpret_cast<half8*>(XP + (size_t)idx * 8) = v;
}

// ---- waits -----------------------------------------------------------------
// scout: lane 0 of the wave polls a flag replica at LLC until it reaches 128,
// then posts the step number to an LDS token for sibling waves.
__device__ __forceinline__ void scout_wait(const unsigned* rep, int* tokLds, int t) {
    if ((threadIdx.x & 63) == 0) {
        unsigned spins = 0;
        while (__hip_atomic_load(rep, __ATOMIC_RELAXED, __HIP_MEMORY_SCOPE_AGENT) < 128u) {
            __builtin_amdgcn_s_sleep(1);
            if (++spins > (1u << 18)) break;   // safety bail: never hang the harness
        }
        __hip_atomic_store(tokLds, t, __ATOMIC_RELAXED, __HIP_MEMORY_SCOPE_WORKGROUP);
    }
    asm volatile("" ::: "memory");
}

__device__ __forceinline__ void lds_wait(const int* tokLds, int t) {
    unsigned spins = 0;
    while (__hip_atomic_load(tokLds, __ATOMIC_RELAXED, __HIP_MEMORY_SCOPE_WORKGROUP) < t) {
        __builtin_amdgcn_s_sleep(1);
        if (++spins > (1u << 20)) break;
    }
    asm volatile("" ::: "memory");
}

struct FArgs {
    const _Float16* XP;
    const _Float16* WP0;
    const _Float16* WP1;
    const float* bp0;
    const float* bp1;
    _Float16* h1r;     // ring: (Tt+1) slabs of HPACK halves; slab j = h1[j-1]
    _Float16* h2r;     // ring: (Tt+1) slabs
    unsigned* h1f;     // flags: [t][8 replicas] stride 32 words
    unsigned* h2f;
    float* out;
};

__global__ __launch_bounds__(1024, 4) void lstm_fused(FArgs a) {
    extern __shared__ char smem[];
    _Float16* wlds = (_Float16*)smem;                          // 128 KB weights
    float* zp = (float*)(smem + WLDS_BYTES);                   // [8][16][17] f32
    _Float16* hstage = (_Float16*)(smem + WLDS_BYTES + ZP_FLOATS * 4);   // [64][8]
    int* tok = (int*)(smem + WLDS_BYTES + ZP_FLOATS * 4 + HSTAGE_BYTES); // [2]

    const int tid = threadIdx.x;
    const int layer = blockIdx.x >> 7;     // 0 or 1
    const int cg = blockIdx.x & 127;       // colgroup: packed cols [cg*32, cg*32+32)
    const int rep = cg & 7;                // this block's flag replica

    // ---- stage this block's weight slice (2 n-tiles, contiguous in B-pack) ----
    const _Float16* wsrc = (layer ? a.WP1 : a.WP0) + (size_t)cg * 65536;
    for (int i = tid; i < 8192; i += 1024)
        ((half8*)wlds)[i] = ((const half8*)wsrc)[i];
    for (int i = tid; i < (int)ZP_FLOATS; i += 1024) zp[i] = 0.f;
    if (tid == 0) { tok[0] = -1; tok[1] = -1; }

    // ---- per-gate-thread persistent state ----
    float creg = 0.f;
    float bias4[4] = {0.f, 0.f, 0.f, 0.f};
    if (tid < 512) {
        int hl = tid & 7;
        const float* bp = layer ? a.bp1 : a.bp0;
#pragma unroll
        for (int g = 0; g < 4; ++g) bias4[g] = bp[cg * 32 + hl * 4 + g];
    }
    __syncthreads();

    const int lane = tid & 63, wv = tid >> 6;
    const int mt = wv & 3, kq = wv >> 2;           // 4 m-tiles x 4 K-quarters
    const int r0 = (lane >> 4) * 4, ccc = lane & 15;
    const int ktL = (kq & 1) * 16;                 // kt offset within the 32-kt source slab

    for (int t = 0; t < Tt; ++t) {
        // ---- phase 0: per-wave readiness waits ----
        if (layer == 0) {
            if (kq >= 2 && t > 0) {                      // h1[t-1] consumers
                if (wv == 8) scout_wait(a.h1f + ((size_t)(t - 1) * 8 + rep) * 32, tok + 0, t);
                else         lds_wait(tok + 0, t);
            }
        } else {
            if (kq < 2) {                                // h1[t] consumers
                if (wv == 0) scout_wait(a.h1f + ((size_t)t * 8 + rep) * 32, tok + 0, t);
                else         lds_wait(tok + 0, t);
            } else if (t > 0) {                          // h2[t-1] consumers
                if (wv == 8) scout_wait(a.h2f + ((size_t)(t - 1) * 8 + rep) * 32, tok + 1, t);
                else         lds_wait(tok + 1, t);
            }
        }

        // ---- phase 1: GEMM quarter (plain cached loads; ring => no staleness) ----
        const _Float16* srcA;
        if (layer == 0)
            srcA = (kq < 2) ? (a.XP + (size_t)t * HPACK) : (a.h1r + (size_t)t * HPACK);
        else
            srcA = (kq < 2) ? (a.h1r + (size_t)(t + 1) * HPACK) : (a.h2r + (size_t)t * HPACK);

        const half8* ap = (const half8*)srcA + ((size_t)mt * 32 + ktL) * 64 + lane;
        const half8* bq0 = (const half8*)wlds + ((size_t)(0 * 64 + kq * 16)) * 64 + lane;
        const half8* bq1 = (const half8*)wlds + ((size_t)(1 * 64 + kq * 16)) * 64 + lane;
        f32x4 ac0 = {0.f, 0.f, 0.f, 0.f}, ac1 = {0.f, 0.f, 0.f, 0.f};
#pragma unroll
        for (int i = 0; i < 16; ++i) {
            half8 av = ap[i * 64];
            ac0 = __builtin_amdgcn_mfma_f32_16x16x32_f16(av, bq0[i * 64], ac0, 0, 0, 0);
            ac1 = __builtin_amdgcn_mfma_f32_16x16x32_f16(av, bq1[i * 64], ac1, 0, 0, 0);
        }
#pragma unroll
        for (int r = 0; r < 4; ++r) {
            atomicAdd(&zp[((mt * 2 + 0) * 16 + r0 + r) * 17 + ccc], ac0[r]);
            atomicAdd(&zp[((mt * 2 + 1) * 16 + r0 + r) * 17 + ccc], ac1[r]);
        }
        __syncthreads();

        // ---- phase 2: gates ----
        if (tid < 512) {
            int b = tid >> 3, hl = tid & 7;
            float z[4];
#pragma unroll
            for (int g = 0; g < 4; ++g) {
                int c = hl * 4 + g;
                z[g] = zp[(((b >> 4) * 2 + (c >> 4)) * 16 + (b & 15)) * 17 + (c & 15)] + bias4[g];
            }
            float cn = creg * sigmoidf_(z[2] + 1.0f) + sigmoidf_(z[0]) * tanhf(z[1]);
            float hn = tanhf(cn) * sigmoidf_(z[3]);
            creg = cn;
            hstage[b * 8 + hl] = (_Float16)hn;
            if (layer) a.out[(size_t)t * 65536 + (size_t)b * 1024 + (cg * 8 + hl)] = hn;
        }
        __syncthreads();

        // ---- phase 3: publish h slab (write-through 4B stores) + zp re-zero ----
        if (tid < 256) {
            int b = tid >> 2, pr = tid & 3;
            unsigned lo = (unsigned)__builtin_bit_cast(unsigned short, hstage[b * 8 + 2 * pr]);
            unsigned hi = (unsigned)__builtin_bit_cast(unsigned short, hstage[b * 8 + 2 * pr + 1]);
            unsigned val = lo | (hi << 16);
            _Float16* hdst = (layer ? a.h2r : a.h1r) + (size_t)(t + 1) * HPACK;
            size_t dw = (((size_t)(b >> 4) * 32 + (cg >> 2)) * 64 + (size_t)(cg & 3) * 16 + (b & 15)) * 4 + pr;
            __hip_atomic_store((unsigned*)hdst + dw, val, __ATOMIC_RELAXED, __HIP_MEMORY_SCOPE_AGENT);
        }
        for (int i = tid; i < (int)ZP_FLOATS; i += 1024) zp[i] = 0.f;
        __syncthreads();   // drains h stores (vmcnt) + orders zp re-zero

        // ---- phase 4: signal readiness (8 replicas in parallel, fire-and-forget)
        if (tid < 8) {
            unsigned* f = (layer ? a.h2f : a.h1f) + ((size_t)t * 8 + tid) * 32;
            (void)__hip_atomic_fetch_add(f, 1u, __ATOMIC_RELAXED, __HIP_MEMORY_SCOPE_AGENT);
        }
    }
}

// ---------------------------------------------------------------------------
extern "C" void kernel_launch(void* const* d_in, const int* in_sizes, int n_in,
                              void* d_out, int out_size, void* d_ws, size_t ws_size,
                              hipStream_t stream) {
    const float* X  = (const float*)d_in[0];
    const float* W0 = (const float*)d_in[1];
    const float* b0 = (const float*)d_in[2];
    const float* W1 = (const float*)d_in[3];
    const float* b1 = (const float*)d_in[4];
    float* out = (float*)d_out;

    char* ws = (char*)d_ws;
    size_t off = 0;
    auto take = [&](size_t n) -> void* {
        void* r = ws + off;
        off += (n + 255) & ~(size_t)255;
        return r;
    };

    const size_t WPB = (size_t)2048 * Gg * 2;            // 16 MiB per packed W
    _Float16* WP0 = (_Float16*)take(WPB);
    _Float16* WP1 = (_Float16*)take(WPB);
    float* bp0 = (float*)take(Gg * 4);
    float* bp1 = (float*)take(Gg * 4);
    const size_t APB = (size_t)Tt * 64 * 1024 * 2;       // 32 MiB X A-pack
    _Float16* XP = (_Float16*)take(APB);
    const size_t RINGB = (size_t)(Tt + 1) * HPACK * 2;   // ~33.6 MiB per ring
    _Float16* h1r = (_Float16*)take(RINGB);
    _Float16* h2r = (_Float16*)take(RINGB);
    const size_t FLAGB = (size_t)Tt * 8 * 32 * 4;        // 256 KiB per flag array
    unsigned* h1f = (unsigned*)take(FLAGB);
    unsigned* h2f = (unsigned*)take(FLAGB);

    // zero: initial h slabs (t=-1) + all flags (dispatch-boundary cache
    // maintenance makes these visible to the persistent kernel).
    hipMemsetAsync(h1r, 0, HPACK * 2, stream);
    hipMemsetAsync(h2r, 0, HPACK * 2, stream);
    hipMemsetAsync(h1f, 0, FLAGB, stream);
    hipMemsetAsync(h2f, 0, FLAGB, stream);

    pack_w_kernel<<<dim3(4096, 2), 256, 0, stream>>>(W0, W1, WP0, WP1);
    pack_bias_kernel<<<32, 256, 0, stream>>>(b0, b1, bp0, bp1);
    pack_a_kernel<<<8192, 256, 0, stream>>>(X, XP);

    hipFuncSetAttribute((const void*)lstm_fused,
                        hipFuncAttributeMaxDynamicSharedMemorySize, SMEM_BYTES);

    FArgs fa{XP, WP0, WP1, bp0, bp1, h1r, h2r, h1f, h2f, out};
    void* kp[] = {&fa};
    hipError_t e = hipLaunchCooperativeKernel((const void*)lstm_fused, dim3(NBLK), dim3(1024),
                                              kp, SMEM_BYTES, stream);
    if (e != hipSuccess) {
        lstm_fused<<<dim3(NBLK), dim3(1024), SMEM_BYTES, stream>>>(fa);
    }
    (void)in_sizes; (void)n_in; (void)out_size; (void)ws_size;
}